// Round 14
// baseline (56.031 us; speedup 1.0000x reference)
//
#include <hip/hip_runtime.h>
#include <hip/hip_bf16.h>

// Conv2dLocal: B=64, C_IN=64, H=W=32, C_OUT=64, 3x3, pad 1, stride 1.
// out[b,o,h,w] = sum_{c,kh,kw} x[b,c,h+kh-1,w+kw-1] * wgt[h,w,o,c,kh,kw] + bias[o,h,w]
//
// Structure = round-13 (best, 44.18 µs) with ONE change: weight-ring loads
// are NON-TEMPORAL (nt). The 151-MB read-once weight stream was evicting the
// xc staging working set (~1.5 MB/XCD, read 9x) from the 4-MB per-XCD L2,
// inflating the serial staging phase at each block head. nt keeps xc L2-hot.
//
// xpose_k: x[bc][hw] f32 -> xc[hw][bc] bf16 (vectorized, transposed-LDS).
// conv_k:  one block per hw (1024 blocks, 512 thr = 8 waves = 2 kh x 4 o4).
//   Patch [64][576] bf16 XOR-swizzled in dynamic LDS; per-wave private
//   pinned-asm weight ring (depth 4, nt), counted vmcnt, no barriers in
//   K-loop; C[64][64] f32 in LDS -> bf16 -> one contiguous 8-KB burst.
// trout_k: tmpb[hw][bo] bf16 -> out[bo][hw] f32, fused bias (vectorized).

typedef __attribute__((ext_vector_type(8))) short short8;
typedef __attribute__((ext_vector_type(4))) float f32x4;

#define PSTR 576  // patch row stride (bf16) = 72 16B-units; 72%8==0 -> swizzle exact

__device__ __forceinline__ void waitlgkm0() {
  asm volatile("s_waitcnt lgkmcnt(0)" ::: "memory");
}

template <int N>
__device__ __forceinline__ void waitvm() {
  asm volatile("s_waitcnt vmcnt(%0)" ::"i"(N) : "memory");
  __builtin_amdgcn_sched_barrier(0);  // rule #18 fence
}

__device__ __forceinline__ unsigned int bf16rne(float f) {
  unsigned int u = __float_as_uint(f);
  return (u + 0x7FFFu + ((u >> 16) & 1u)) >> 16;
}

__global__ __launch_bounds__(256) void xpose_k(const float* __restrict__ x,
                                               unsigned short* __restrict__ xc) {
  __shared__ float tile[64][130];  // [hw][bc], 33,280 B
  int bid = blockIdx.x;            // 32 row-tiles(128 bc) x 16 col-tiles(64 hw)
  int rt = bid >> 4, ct = bid & 15;
  int r0 = rt << 7, c0 = ct << 6;
  int lane = threadIdx.x & 63, wv = threadIdx.x >> 6;
#pragma unroll
  for (int i = 0; i < 32; ++i) {
    int r = (i << 2) + wv;  // bc row 0..127
    tile[lane][r] = x[(size_t)(r0 + r) * 1024 + c0 + lane];  // transposed write
  }
  __syncthreads();
#pragma unroll
  for (int i = 0; i < 16; ++i) {
    int oc = (i << 2) + wv;  // hw col 0..63
    float2 v = *(const float2*)&tile[oc][2 * lane];
    unsigned int pk = bf16rne(v.x) | (bf16rne(v.y) << 16);
    *(unsigned int*)(xc + (size_t)(c0 + oc) * 4096 + r0 + 2 * lane) = pk;
  }
}

__global__ __launch_bounds__(512, 4) void conv_k(const unsigned short* __restrict__ xc,
                                                 const float* __restrict__ wgt,
                                                 unsigned short* __restrict__ tmpb) {
  extern __shared__ unsigned short patch[];  // [64][PSTR] = 73,728 B dynamic

  int bid = blockIdx.x;
  int hw = ((bid & 7) << 7) | (bid >> 3);  // XCD gets 128 contiguous hw
  int h = hw >> 5, w = hw & 31;
  int t = threadIdx.x;

  // ---- stage im2col patch: thread t owns row t>>3, c-octet t&7 ----
  {
    int c8 = t & 7;
    int row = t >> 3;  // 0..63
    uint4 v[9];
#pragma unroll
    for (int tap = 0; tap < 9; ++tap) {
      int y = h + tap / 3 - 1;
      int xw = w + tap % 3 - 1;
      bool valid = ((unsigned)y < 32u) && ((unsigned)xw < 32u);
      uint4 val = make_uint4(0u, 0u, 0u, 0u);
      if (valid)
        val = *(const uint4*)(xc + ((size_t)(y * 32 + xw) << 12) + row * 64 + c8 * 8);
      v[tap] = val;
    }
    unsigned short* dst = patch + row * PSTR;
    int r7b = row & 7;
    const unsigned int* vw = (const unsigned int*)v;
#pragma unroll
    for (int u = 0; u < 9; ++u) {
      unsigned int wd[4];
#pragma unroll
      for (int wi = 0; wi < 4; ++wi) {
        const int kl0 = 8 * u + 2 * wi, kl1 = kl0 + 1;
        const int tapA = kl0 % 9, jA = kl0 / 9;
        const int tapB = kl1 % 9, jB = kl1 / 9;
        const unsigned int selLo = (jA & 1) ? 0x0302u : 0x0100u;
        const unsigned int selHi = (jB & 1) ? 0x0706u : 0x0504u;
        wd[wi] = __builtin_amdgcn_perm(vw[tapB * 4 + (jB >> 1)],
                                       vw[tapA * 4 + (jA >> 1)],
                                       selLo | (selHi << 16));
      }
      int u_abs = 9 * c8 + u;
      int u_swz = (u_abs & ~7) | ((u_abs & 7) ^ r7b);
      *(uint4*)(dst + (u_swz << 3)) = make_uint4(wd[0], wd[1], wd[2], wd[3]);
    }
  }

  // ---- per-wave private weight stream: pinned asm loads, DEPTH-4 ring ----
  int wid = t >> 6, lane = t & 63;
  int o4 = wid & 3, kh = wid >> 2;            // o-tile, K-half
  int l15 = lane & 15, l4 = lane >> 4;
  const float* wb = wgt + (size_t)hw * 36864;  // [64 o][576 k] f32
  const float* wp = wb + (size_t)(o4 * 16 + l15) * 576 + kh * 288 + l4 * 8;

  float4 pf[4][2];  // 32 VGPRs; all indices static after unroll -> registers

  // nt: non-temporal — read-once weight stream must not evict xc from L2
#define ISSUE(slot, step)                                              \
  do {                                                                 \
    const float* _a = wp + (step) * 32;                                \
    asm volatile("global_load_dwordx4 %0, %2, off nt\n\t"              \
                 "global_load_dwordx4 %1, %2, off offset:16 nt"        \
                 : "=&v"(pf[slot][0]), "=&v"(pf[slot][1])              \
                 : "v"(_a)                                             \
                 : "memory");                                          \
  } while (0)

  ISSUE(0, 0); ISSUE(1, 1); ISSUE(2, 2); ISSUE(3, 3);

  waitlgkm0();                          // own patch ds_writes complete
  __builtin_amdgcn_sched_barrier(0);
  __builtin_amdgcn_s_barrier();         // patch visible; 8 weight loads in flight

  int l7 = l15 & 7;
  const unsigned short* apE = patch + l15 * PSTR + ((l4 ^ l7) << 3);
  const unsigned short* apO = patch + l15 * PSTR + (((4 + l4) ^ l7) << 3);
  int kh9 = kh * 9;

  f32x4 acc0 = {0.f, 0.f, 0.f, 0.f};
  f32x4 acc1 = acc0, acc2 = acc0, acc3 = acc0;

  union S8U { short8 s; unsigned int u[4]; };
  auto pack = [](const float4& lo, const float4& hi) -> short8 {
    S8U r;  // truncate f32->bf16 via v_perm (weights)
    r.u[0] = __builtin_amdgcn_perm(__float_as_uint(lo.y), __float_as_uint(lo.x), 0x07060302u);
    r.u[1] = __builtin_amdgcn_perm(__float_as_uint(lo.w), __float_as_uint(lo.z), 0x07060302u);
    r.u[2] = __builtin_amdgcn_perm(__float_as_uint(hi.y), __float_as_uint(hi.x), 0x07060302u);
    r.u[3] = __builtin_amdgcn_perm(__float_as_uint(hi.w), __float_as_uint(hi.z), 0x07060302u);
    return r.s;
  };

  // 9 K-steps/wave, NO barriers. 18 loads: 8 prologue + 2*5 refills (s=0..4).
  // N = issued - 2(s+1) = 6,6,6,6,6,6,4,2,0.
#pragma unroll
  for (int s = 0; s < 9; ++s) {
    const int slot = s & 3;
    if      (s <= 5) waitvm<6>();
    else if (s == 6) waitvm<4>();
    else if (s == 7) waitvm<2>();
    else             waitvm<0>();

    short8 b0 = pack(pf[slot][0], pf[slot][1]);

    int S = kh9 + s;  // global K-step 0..17 (wave-uniform)
    const unsigned short* ab = ((S & 1) ? apO : apE) + (S >> 1) * 64;
    short8 a0 = *(const short8*)ab;                 // ds_read_b128 x4
    short8 a1 = *(const short8*)(ab + 16 * PSTR);
    short8 a2 = *(const short8*)(ab + 32 * PSTR);
    short8 a3 = *(const short8*)(ab + 48 * PSTR);

    if (s + 4 < 9) ISSUE(slot, s + 4);              // refill slot just consumed

    acc0 = __builtin_amdgcn_mfma_f32_16x16x32_bf16(a0, b0, acc0, 0, 0, 0);
    acc1 = __builtin_amdgcn_mfma_f32_16x16x32_bf16(a1, b0, acc1, 0, 0, 0);
    acc2 = __builtin_amdgcn_mfma_f32_16x16x32_bf16(a2, b0, acc2, 0, 0, 0);
    acc3 = __builtin_amdgcn_mfma_f32_16x16x32_bf16(a3, b0, acc3, 0, 0, 0);
  }
#undef ISSUE

  // ---- assemble C[64 b][64 o] f32 in LDS (stride 68: 2-way-free banks) ----
  __syncthreads();  // all waves done reading patch; ring drained (s=8 -> vmcnt 0)
  float* C = (float*)patch;  // 64*68*4 = 17,408 B, fits in patch region
  int o = (o4 << 4) + l15;
  int m0 = l4 << 2;
  if (kh == 0) {  // C/D layout: col=lane&15 (o), row=(lane>>4)*4+reg (b)
#pragma unroll
    for (int r = 0; r < 4; ++r) {
      C[(m0 + r) * 68 + o] = acc0[r];
      C[(m0 + r + 16) * 68 + o] = acc1[r];
      C[(m0 + r + 32) * 68 + o] = acc2[r];
      C[(m0 + r + 48) * 68 + o] = acc3[r];
    }
  }
  __syncthreads();
  if (kh == 1) {
#pragma unroll
    for (int r = 0; r < 4; ++r) {
      C[(m0 + r) * 68 + o] += acc0[r];
      C[(m0 + r + 16) * 68 + o] += acc1[r];
      C[(m0 + r + 32) * 68 + o] += acc2[r];
      C[(m0 + r + 48) * 68 + o] += acc3[r];
    }
  }
  __syncthreads();

  // ---- contiguous 8-KB bf16 burst: tmpb[hw][b*64+o] ----
  {
    int b = t >> 3, o0 = (t & 7) << 3;  // 8 values within one b-row
    const float* src = C + b * 68 + o0;
    unsigned int wd0 = bf16rne(src[0]) | (bf16rne(src[1]) << 16);
    unsigned int wd1 = bf16rne(src[2]) | (bf16rne(src[3]) << 16);
    unsigned int wd2 = bf16rne(src[4]) | (bf16rne(src[5]) << 16);
    unsigned int wd3 = bf16rne(src[6]) | (bf16rne(src[7]) << 16);
    unsigned short* dst = tmpb + ((size_t)hw << 12) + (t << 3);
    *(uint4*)dst = make_uint4(wd0, wd1, wd2, wd3);
  }
}

__global__ __launch_bounds__(256) void trout_k(const unsigned short* __restrict__ tmpb,
                                               const float* __restrict__ bias,
                                               float* __restrict__ out) {
  __shared__ float tile[128][65];  // [bo][hw], 33,280 B
  int bid = blockIdx.x;            // 32 bo-tiles(128) x 16 hw-tiles(64)
  int bt = bid >> 4, ht = bid & 15;
  int bo0 = bt << 7, hw0 = ht << 6;
  int lane = threadIdx.x & 63, wv = threadIdx.x >> 6;
#pragma unroll
  for (int i = 0; i < 16; ++i) {
    int r = (i << 2) + wv;  // hw row 0..63
    unsigned int u =
        *(const unsigned int*)(tmpb + (size_t)(hw0 + r) * 4096 + bo0 + 2 * lane);
    tile[2 * lane][r] = __uint_as_float(u << 16);              // bf16 lo -> f32
    tile[2 * lane + 1][r] = __uint_as_float(u & 0xFFFF0000u);  // bf16 hi -> f32
  }
  __syncthreads();
#pragma unroll
  for (int i = 0; i < 32; ++i) {
    int j = (i << 2) + wv;  // bo col 0..127
    int bo = bo0 + j;
    out[(size_t)bo * 1024 + hw0 + lane] =
        tile[j][lane] + bias[(bo & 63) * 1024 + hw0 + lane];
  }
}

extern "C" void kernel_launch(void* const* d_in, const int* in_sizes, int n_in,
                              void* d_out, int out_size, void* d_ws, size_t ws_size,
                              hipStream_t stream) {
  const float* x = (const float*)d_in[0];
  const float* wgt = (const float*)d_in[1];
  const float* bias = (const float*)d_in[2];
  float* out = (float*)d_out;
  unsigned short* xc = (unsigned short*)d_ws;                    // 8,388,608 B
  unsigned short* tmpb = (unsigned short*)((char*)d_ws + (8u << 20));  // 8,388,608 B

  const int conv_lds = 64 * PSTR * 2;  // 73,728 B dynamic LDS
  (void)hipFuncSetAttribute((const void*)conv_k,
                            hipFuncAttributeMaxDynamicSharedMemorySize, conv_lds);

  hipLaunchKernelGGL(xpose_k, dim3(512), dim3(256), 0, stream, x, xc);
  hipLaunchKernelGGL(conv_k, dim3(1024), dim3(512), conv_lds, stream, xc, wgt, tmpb);
  hipLaunchKernelGGL(trout_k, dim3(512), dim3(256), 0, stream, tmpb, bias, out);
}

// Round 15
// 44.213 us; speedup vs baseline: 1.2673x; 1.2673x over previous
//
#include <hip/hip_runtime.h>
#include <hip/hip_bf16.h>

// Conv2dLocal: B=64, C_IN=64, H=W=32, C_OUT=64, 3x3, pad 1, stride 1.
// out[b,o,h,w] = sum_{c,kh,kw} x[b,c,h+kh-1,w+kw-1] * wgt[h,w,o,c,kh,kw] + bias[o,h,w]
//
// Round-13 structure (best, 44.18 µs). r14's nt experiment REGRESSED 12 µs —
// the weight stream needs normal L2 caching (request merging); reverted.
// This round: ring depth 4 -> 6 (48 VGPRs, ~110 total < 128 cap) to cover
// more cold-HBM latency at the serial block-head. Ladder: N =
// 12+2*min(s,3) - 2(s+1) = 10,10,10,10,8,6,4,2,0.
//
// xpose_k: x[bc][hw] f32 -> xc[hw][bc] bf16 (vectorized, transposed-LDS).
// conv_k:  one block per hw (1024 blocks, 512 thr = 8 waves = 2 kh x 4 o4).
//   Patch [64][576] bf16 XOR-swizzled in dynamic LDS; per-wave private
//   pinned-asm weight ring (depth 6), counted vmcnt, no barriers in K-loop;
//   C[64][64] f32 in LDS -> bf16 -> one contiguous 8-KB burst to tmpb.
// trout_k: tmpb[hw][bo] bf16 -> out[bo][hw] f32, fused bias (vectorized).

typedef __attribute__((ext_vector_type(8))) short short8;
typedef __attribute__((ext_vector_type(4))) float f32x4;

#define PSTR 576  // patch row stride (bf16) = 72 16B-units; 72%8==0 -> swizzle exact

__device__ __forceinline__ void waitlgkm0() {
  asm volatile("s_waitcnt lgkmcnt(0)" ::: "memory");
}

template <int N>
__device__ __forceinline__ void waitvm() {
  asm volatile("s_waitcnt vmcnt(%0)" ::"i"(N) : "memory");
  __builtin_amdgcn_sched_barrier(0);  // rule #18 fence
}

__device__ __forceinline__ unsigned int bf16rne(float f) {
  unsigned int u = __float_as_uint(f);
  return (u + 0x7FFFu + ((u >> 16) & 1u)) >> 16;
}

__global__ __launch_bounds__(256) void xpose_k(const float* __restrict__ x,
                                               unsigned short* __restrict__ xc) {
  __shared__ float tile[64][130];  // [hw][bc], 33,280 B
  int bid = blockIdx.x;            // 32 row-tiles(128 bc) x 16 col-tiles(64 hw)
  int rt = bid >> 4, ct = bid & 15;
  int r0 = rt << 7, c0 = ct << 6;
  int lane = threadIdx.x & 63, wv = threadIdx.x >> 6;
#pragma unroll
  for (int i = 0; i < 32; ++i) {
    int r = (i << 2) + wv;  // bc row 0..127
    tile[lane][r] = x[(size_t)(r0 + r) * 1024 + c0 + lane];  // transposed write
  }
  __syncthreads();
#pragma unroll
  for (int i = 0; i < 16; ++i) {
    int oc = (i << 2) + wv;  // hw col 0..63
    float2 v = *(const float2*)&tile[oc][2 * lane];
    unsigned int pk = bf16rne(v.x) | (bf16rne(v.y) << 16);
    *(unsigned int*)(xc + (size_t)(c0 + oc) * 4096 + r0 + 2 * lane) = pk;
  }
}

__global__ __launch_bounds__(512, 4) void conv_k(const unsigned short* __restrict__ xc,
                                                 const float* __restrict__ wgt,
                                                 unsigned short* __restrict__ tmpb) {
  extern __shared__ unsigned short patch[];  // [64][PSTR] = 73,728 B dynamic

  int bid = blockIdx.x;
  int hw = ((bid & 7) << 7) | (bid >> 3);  // XCD gets 128 contiguous hw
  int h = hw >> 5, w = hw & 31;
  int t = threadIdx.x;

  // ---- stage im2col patch: thread t owns row t>>3, c-octet t&7 ----
  {
    int c8 = t & 7;
    int row = t >> 3;  // 0..63
    uint4 v[9];
#pragma unroll
    for (int tap = 0; tap < 9; ++tap) {
      int y = h + tap / 3 - 1;
      int xw = w + tap % 3 - 1;
      bool valid = ((unsigned)y < 32u) && ((unsigned)xw < 32u);
      uint4 val = make_uint4(0u, 0u, 0u, 0u);
      if (valid)
        val = *(const uint4*)(xc + ((size_t)(y * 32 + xw) << 12) + row * 64 + c8 * 8);
      v[tap] = val;
    }
    unsigned short* dst = patch + row * PSTR;
    int r7b = row & 7;
    const unsigned int* vw = (const unsigned int*)v;
#pragma unroll
    for (int u = 0; u < 9; ++u) {
      unsigned int wd[4];
#pragma unroll
      for (int wi = 0; wi < 4; ++wi) {
        const int kl0 = 8 * u + 2 * wi, kl1 = kl0 + 1;
        const int tapA = kl0 % 9, jA = kl0 / 9;
        const int tapB = kl1 % 9, jB = kl1 / 9;
        const unsigned int selLo = (jA & 1) ? 0x0302u : 0x0100u;
        const unsigned int selHi = (jB & 1) ? 0x0706u : 0x0504u;
        wd[wi] = __builtin_amdgcn_perm(vw[tapB * 4 + (jB >> 1)],
                                       vw[tapA * 4 + (jA >> 1)],
                                       selLo | (selHi << 16));
      }
      int u_abs = 9 * c8 + u;
      int u_swz = (u_abs & ~7) | ((u_abs & 7) ^ r7b);
      *(uint4*)(dst + (u_swz << 3)) = make_uint4(wd[0], wd[1], wd[2], wd[3]);
    }
  }

  // ---- per-wave private weight stream: pinned asm loads, DEPTH-6 ring ----
  int wid = t >> 6, lane = t & 63;
  int o4 = wid & 3, kh = wid >> 2;            // o-tile, K-half
  int l15 = lane & 15, l4 = lane >> 4;
  const float* wb = wgt + (size_t)hw * 36864;  // [64 o][576 k] f32
  const float* wp = wb + (size_t)(o4 * 16 + l15) * 576 + kh * 288 + l4 * 8;

  float4 pf[6][2];  // 48 VGPRs; all indices static after unroll -> registers

#define ISSUE(slot, step)                                              \
  do {                                                                 \
    const float* _a = wp + (step) * 32;                                \
    asm volatile("global_load_dwordx4 %0, %2, off\n\t"                 \
                 "global_load_dwordx4 %1, %2, off offset:16"           \
                 : "=&v"(pf[slot][0]), "=&v"(pf[slot][1])              \
                 : "v"(_a)                                             \
                 : "memory");                                          \
  } while (0)

  ISSUE(0, 0); ISSUE(1, 1); ISSUE(2, 2);
  ISSUE(3, 3); ISSUE(4, 4); ISSUE(5, 5);

  waitlgkm0();                          // own patch ds_writes complete
  __builtin_amdgcn_sched_barrier(0);
  __builtin_amdgcn_s_barrier();         // patch visible; 12 weight loads in flight

  int l7 = l15 & 7;
  const unsigned short* apE = patch + l15 * PSTR + ((l4 ^ l7) << 3);
  const unsigned short* apO = patch + l15 * PSTR + (((4 + l4) ^ l7) << 3);
  int kh9 = kh * 9;

  f32x4 acc0 = {0.f, 0.f, 0.f, 0.f};
  f32x4 acc1 = acc0, acc2 = acc0, acc3 = acc0;

  union S8U { short8 s; unsigned int u[4]; };
  auto pack = [](const float4& lo, const float4& hi) -> short8 {
    S8U r;  // truncate f32->bf16 via v_perm (weights)
    r.u[0] = __builtin_amdgcn_perm(__float_as_uint(lo.y), __float_as_uint(lo.x), 0x07060302u);
    r.u[1] = __builtin_amdgcn_perm(__float_as_uint(lo.w), __float_as_uint(lo.z), 0x07060302u);
    r.u[2] = __builtin_amdgcn_perm(__float_as_uint(hi.y), __float_as_uint(hi.x), 0x07060302u);
    r.u[3] = __builtin_amdgcn_perm(__float_as_uint(hi.w), __float_as_uint(hi.z), 0x07060302u);
    return r.s;
  };

  // 9 K-steps/wave, NO barriers. 18 loads: 12 prologue + 2*3 refills (s=0..2).
  // Issued = 12 + 2*min(s,3); N = issued - 2(s+1) = 10,10,10,10,8,6,4,2,0.
#pragma unroll
  for (int s = 0; s < 9; ++s) {
    const int slot = s % 6;  // compile-time after unroll
    if      (s <= 3) waitvm<10>();
    else if (s == 4) waitvm<8>();
    else if (s == 5) waitvm<6>();
    else if (s == 6) waitvm<4>();
    else if (s == 7) waitvm<2>();
    else             waitvm<0>();

    short8 b0 = pack(pf[slot][0], pf[slot][1]);

    int S = kh9 + s;  // global K-step 0..17 (wave-uniform)
    const unsigned short* ab = ((S & 1) ? apO : apE) + (S >> 1) * 64;
    short8 a0 = *(const short8*)ab;                 // ds_read_b128 x4
    short8 a1 = *(const short8*)(ab + 16 * PSTR);
    short8 a2 = *(const short8*)(ab + 32 * PSTR);
    short8 a3 = *(const short8*)(ab + 48 * PSTR);

    if (s + 6 < 9) ISSUE(slot, s + 6);              // refill slot just consumed

    acc0 = __builtin_amdgcn_mfma_f32_16x16x32_bf16(a0, b0, acc0, 0, 0, 0);
    acc1 = __builtin_amdgcn_mfma_f32_16x16x32_bf16(a1, b0, acc1, 0, 0, 0);
    acc2 = __builtin_amdgcn_mfma_f32_16x16x32_bf16(a2, b0, acc2, 0, 0, 0);
    acc3 = __builtin_amdgcn_mfma_f32_16x16x32_bf16(a3, b0, acc3, 0, 0, 0);
  }
#undef ISSUE

  // ---- assemble C[64 b][64 o] f32 in LDS (stride 68: 2-way-free banks) ----
  __syncthreads();  // all waves done reading patch; ring drained (s=8 -> vmcnt 0)
  float* C = (float*)patch;  // 64*68*4 = 17,408 B, fits in patch region
  int o = (o4 << 4) + l15;
  int m0 = l4 << 2;
  if (kh == 0) {  // C/D layout: col=lane&15 (o), row=(lane>>4)*4+reg (b)
#pragma unroll
    for (int r = 0; r < 4; ++r) {
      C[(m0 + r) * 68 + o] = acc0[r];
      C[(m0 + r + 16) * 68 + o] = acc1[r];
      C[(m0 + r + 32) * 68 + o] = acc2[r];
      C[(m0 + r + 48) * 68 + o] = acc3[r];
    }
  }
  __syncthreads();
  if (kh == 1) {
#pragma unroll
    for (int r = 0; r < 4; ++r) {
      C[(m0 + r) * 68 + o] += acc0[r];
      C[(m0 + r + 16) * 68 + o] += acc1[r];
      C[(m0 + r + 32) * 68 + o] += acc2[r];
      C[(m0 + r + 48) * 68 + o] += acc3[r];
    }
  }
  __syncthreads();

  // ---- contiguous 8-KB bf16 burst: tmpb[hw][b*64+o] ----
  {
    int b = t >> 3, o0 = (t & 7) << 3;  // 8 values within one b-row
    const float* src = C + b * 68 + o0;
    unsigned int wd0 = bf16rne(src[0]) | (bf16rne(src[1]) << 16);
    unsigned int wd1 = bf16rne(src[2]) | (bf16rne(src[3]) << 16);
    unsigned int wd2 = bf16rne(src[4]) | (bf16rne(src[5]) << 16);
    unsigned int wd3 = bf16rne(src[6]) | (bf16rne(src[7]) << 16);
    unsigned short* dst = tmpb + ((size_t)hw << 12) + (t << 3);
    *(uint4*)dst = make_uint4(wd0, wd1, wd2, wd3);
  }
}

__global__ __launch_bounds__(256) void trout_k(const unsigned short* __restrict__ tmpb,
                                               const float* __restrict__ bias,
                                               float* __restrict__ out) {
  __shared__ float tile[128][65];  // [bo][hw], 33,280 B
  int bid = blockIdx.x;            // 32 bo-tiles(128) x 16 hw-tiles(64)
  int bt = bid >> 4, ht = bid & 15;
  int bo0 = bt << 7, hw0 = ht << 6;
  int lane = threadIdx.x & 63, wv = threadIdx.x >> 6;
#pragma unroll
  for (int i = 0; i < 16; ++i) {
    int r = (i << 2) + wv;  // hw row 0..63
    unsigned int u =
        *(const unsigned int*)(tmpb + (size_t)(hw0 + r) * 4096 + bo0 + 2 * lane);
    tile[2 * lane][r] = __uint_as_float(u << 16);              // bf16 lo -> f32
    tile[2 * lane + 1][r] = __uint_as_float(u & 0xFFFF0000u);  // bf16 hi -> f32
  }
  __syncthreads();
#pragma unroll
  for (int i = 0; i < 32; ++i) {
    int j = (i << 2) + wv;  // bo col 0..127
    int bo = bo0 + j;
    out[(size_t)bo * 1024 + hw0 + lane] =
        tile[j][lane] + bias[(bo & 63) * 1024 + hw0 + lane];
  }
}

extern "C" void kernel_launch(void* const* d_in, const int* in_sizes, int n_in,
                              void* d_out, int out_size, void* d_ws, size_t ws_size,
                              hipStream_t stream) {
  const float* x = (const float*)d_in[0];
  const float* wgt = (const float*)d_in[1];
  const float* bias = (const float*)d_in[2];
  float* out = (float*)d_out;
  unsigned short* xc = (unsigned short*)d_ws;                    // 8,388,608 B
  unsigned short* tmpb = (unsigned short*)((char*)d_ws + (8u << 20));  // 8,388,608 B

  const int conv_lds = 64 * PSTR * 2;  // 73,728 B dynamic LDS
  (void)hipFuncSetAttribute((const void*)conv_k,
                            hipFuncAttributeMaxDynamicSharedMemorySize, conv_lds);

  hipLaunchKernelGGL(xpose_k, dim3(512), dim3(256), 0, stream, x, xc);
  hipLaunchKernelGGL(conv_k, dim3(1024), dim3(512), conv_lds, stream, xc, wgt, tmpb);
  hipLaunchKernelGGL(trout_k, dim3(512), dim3(256), 0, stream, tmpb, bias, out);
}